// Round 6
// baseline (226.279 us; speedup 1.0000x reference)
//
#include <hip/hip_runtime.h>

// Problem constants: B=512, T=4096, C=7, H=3 ; N = 2,097,152 rows
constexpr long long N_ROWS = 512LL * 4096LL;
constexpr int BLOCK = 256;              // 4 waves
constexpr int CHUNK = 256;              // rows per chunk
constexpr int CPB   = 8;                // chunks per block
constexpr int NBLOCKS = (int)(N_ROWS / ((long long)CHUNK * CPB));  // 1024

// Per-buffer LDS layout (float words):
//   [0,5376)    out: 3 heads * 256 rows * 7
//   [5376,6144) labels: 256*3 int32
//   [6144,6912) reward: 256*3
//   [6912,7168) mask: 256
constexpr int BUFW = 7168;              // 28672 B; double = 57344 B -> 2 blocks/CU

__device__ __forceinline__ void async16(const float* g, float* l) {
    __builtin_amdgcn_global_load_lds(
        (const __attribute__((address_space(1))) unsigned int*)g,
        (__attribute__((address_space(3))) unsigned int*)l,
        16, 0, 0);
}

// Raw barrier with compiler-motion fences on both sides: ds_reads/writes may not
// migrate across (s_barrier intrinsic alone is not a compiler memory fence).
#define BARRIER() do {                       \
    asm volatile("" ::: "memory");           \
    __builtin_amdgcn_s_barrier();            \
    asm volatile("" ::: "memory");           \
} while (0)

// R6 synthesis of R0/R1/R4/R5 evidence:
//  - R1/R5 (direct-to-reg): TA-request-bound — 112-B lane stride => ~56 lines
//    per dwordx4 (~7x inflation), warm-L3 == cold => latency/request bound.
//  - R0 (LDS staged, __syncthreads): coalesced, but vmcnt(0)+barrier drain per
//    chunk serialized the pipeline at 2 blocks/CU.
//  - R4 (per-wave pipeline): counted vmcnt works, but 0.75 waves/SIMD starved
//    the CU, and compiler-tracked side-register loads inserted under-counted
//    waits (stealth drains).
// This kernel: EVERYTHING staged through LDS with wave-specialized whole-wave
// async16 (waves 0-2: one head each, 7 instrs; wave 3: labels+reward+mask,
// 3+3+1 = 7 instrs -> uniform per-wave vmcnt), double-buffered, counted
// s_waitcnt vmcnt(7) + raw s_barrier (never vmcnt(0) in the loop), second
// barrier after compute as the WAR guard before the buffer is restaged.
__global__ __launch_bounds__(BLOCK) void shortloss_main(
    const float* __restrict__ out0,
    const float* __restrict__ out1,
    const float* __restrict__ out2,
    const int*   __restrict__ labels,   // [N,3] int32
    const float* __restrict__ mask,     // [N]
    const float* __restrict__ reward,   // [N,3]
    float4*      __restrict__ partials) // [NBLOCKS]
{
    __shared__ float lds[2 * BUFW];
    const int tid = threadIdx.x;
    const int wv  = tid >> 6;           // wave id 0..3
    const int ln  = tid & 63;           // lane
    const long long c0 = (long long)blockIdx.x * CPB;
    const float* outs[3] = {out0, out1, out2};

    // Whole-wave staging, wave-specialized; exactly 7 async16 per wave per chunk.
    auto stage = [&](long long c, int b) {
        float* buf = lds + b * BUFW;
        if (wv < 3) {
            const float* src = outs[wv] + c * 1792;        // 256 rows * 7 floats
            float*       dst = buf + wv * 1792;
            #pragma unroll
            for (int j = 0; j < 7; ++j)
                async16(src + j * 256 + 4 * (size_t)ln, dst + j * 256 + 4 * ln);
        } else {
            const float* lsrc = (const float*)labels + c * 768;
            const float* rsrc = reward + c * 768;
            #pragma unroll
            for (int j = 0; j < 3; ++j)
                async16(lsrc + j * 256 + 4 * (size_t)ln, buf + 5376 + j * 256 + 4 * ln);
            #pragma unroll
            for (int j = 0; j < 3; ++j)
                async16(rsrc + j * 256 + 4 * (size_t)ln, buf + 6144 + j * 256 + 4 * ln);
            async16(mask + c * 256 + 4 * (size_t)ln, buf + 6912 + 4 * ln);
        }
    };

    float L = 0.0f;
    int   C = 0, V = 0;

    // One row per lane: r = 64*wv + ln. LDS strides 7 (outs) and 3 (side) are
    // coprime with 32 banks -> 2-way aliasing only (free on wave64).
    auto compute = [&](int b) {
        const float* buf  = lds + b * BUFW;
        const int*   labp = (const int*)(buf + 5376);
        const int r = (wv << 6) + ln;
        const bool valid = buf[6912 + r] < 0.5f;
        V += valid ? 1 : 0;
        int   ok   = 1;
        float lsum = 0.0f;
        #pragma unroll
        for (int h = 0; h < 3; ++h) {
            const int lbl = labp[r * 3 + h];
            const float* vr = buf + h * 1792 + r * 7;
            float v[7];
            #pragma unroll
            for (int cc = 0; cc < 7; ++cc) v[cc] = vr[cc];

            // argmax, strict > (first-max tie-break, matches jnp.argmax)
            float best = v[0]; int bestc = 0;
            #pragma unroll
            for (int cc = 1; cc < 7; ++cc)
                if (v[cc] > best) { best = v[cc]; bestc = cc; }

            // gather true-class prob via select chain (no dynamic reg index)
            float opv = v[0];
            #pragma unroll
            for (int cc = 1; cc < 7; ++cc)
                opv = (lbl == cc) ? v[cc] : opv;

            lsum += __logf(opv) * buf[6144 + r * 3 + h];
            ok &= (bestc == lbl) ? 1 : 0;
        }
        L += valid ? lsum : 0.0f;
        C += (valid && ok) ? 1 : 0;
    };

    // ---- pipeline: counted vmcnt, two raw barriers per chunk, no drains ----
    stage(c0, 0);
    #pragma unroll
    for (int k = 0; k < CPB; ++k) {
        if (k + 1 < CPB) {
            stage(c0 + k + 1, (k + 1) & 1);                 // 7 newer loads in flight
            asm volatile("s_waitcnt vmcnt(7)" ::: "memory"); // chunk k fully staged
        } else {
            asm volatile("s_waitcnt vmcnt(0)" ::: "memory"); // last chunk staged
        }
        BARRIER();            // all waves' chunk-k staging visible
        compute(k & 1);
        BARRIER();            // WAR guard: buf[k&1] may be restaged next iter
    }

    // ---- block reduction ----
    #pragma unroll
    for (int off = 32; off > 0; off >>= 1) {
        L += __shfl_down(L, off, 64);
        C += __shfl_down(C, off, 64);
        V += __shfl_down(V, off, 64);
    }
    __shared__ float sL[BLOCK / 64];
    __shared__ int   sC[BLOCK / 64], sV[BLOCK / 64];
    if (ln == 0) { sL[wv] = L; sC[wv] = C; sV[wv] = V; }
    __syncthreads();
    if (tid == 0) {
        float l = 0.0f; int cc = 0, vv = 0;
        #pragma unroll
        for (int w = 0; w < BLOCK / 64; ++w) { l += sL[w]; cc += sC[w]; vv += sV[w]; }
        partials[blockIdx.x] = make_float4(l, (float)cc, (float)vv, 0.0f);
    }
}

__global__ __launch_bounds__(256) void shortloss_reduce(
    const float4* __restrict__ partials,
    float* __restrict__ out)
{
    float L = 0.0f, C = 0.0f, V = 0.0f;
    for (int i = threadIdx.x; i < NBLOCKS; i += 256) {
        float4 p = partials[i];
        L += p.x; C += p.y; V += p.z;
    }
    #pragma unroll
    for (int off = 32; off > 0; off >>= 1) {
        L += __shfl_down(L, off, 64);
        C += __shfl_down(C, off, 64);
        V += __shfl_down(V, off, 64);
    }
    __shared__ float sL[4], sC[4], sV[4];
    const int wave = threadIdx.x >> 6;
    if ((threadIdx.x & 63) == 0) { sL[wave] = L; sC[wave] = C; sV[wave] = V; }
    __syncthreads();
    if (threadIdx.x == 0) {
        float l = 0.0f, c = 0.0f, v = 0.0f;
        #pragma unroll
        for (int w = 0; w < 4; ++w) { l += sL[w]; c += sC[w]; v += sV[w]; }
        out[0] = -l / v;
        out[1] = c;
        out[2] = v;
    }
}

extern "C" void kernel_launch(void* const* d_in, const int* in_sizes, int n_in,
                              void* d_out, int out_size, void* d_ws, size_t ws_size,
                              hipStream_t stream) {
    const float* out0   = (const float*)d_in[0];
    const float* out1   = (const float*)d_in[1];
    const float* out2   = (const float*)d_in[2];
    const int*   labels = (const int*)  d_in[3];
    const float* mask   = (const float*)d_in[4];
    const float* reward = (const float*)d_in[5];

    float4* partials = (float4*)d_ws;   // 1024 * 16 B = 16 KB

    shortloss_main<<<NBLOCKS, BLOCK, 0, stream>>>(
        out0, out1, out2, labels, mask, reward, partials);
    shortloss_reduce<<<1, 256, 0, stream>>>(partials, (float*)d_out);
}